// Round 15
// baseline (403.523 us; speedup 1.0000x reference)
//
#include <hip/hip_runtime.h>
#include <hip/hip_bf16.h>
#include <cstdint>

#define TK 2048      // tokens (2*1024)
#define HD 2048      // hidden
#define ID 1024      // intermediate
#define NE 16        // routed experts
#define NG 17        // groups incl shared expert (g==16)
#define TOPK 4
#define SLOTS (TK*TOPK)       // 8192 routed rows
#define ROWS_ALL (SLOTS+TK)   // 10240 incl shared
#define IH (ID*HD)            // 2,097,152 elems per expert matrix
#define MAXT 96               // max 128-row M-tiles across all groups

typedef __attribute__((ext_vector_type(4))) float f32x4;
typedef __attribute__((ext_vector_type(16))) float f32x16;
typedef __attribute__((ext_vector_type(8))) short s16x8;
typedef unsigned short u16;
typedef unsigned long long u64;

__device__ __forceinline__ u16 f2bf(float f){
  union { float f; uint32_t u; } v; v.f = f;
  uint32_t r = v.u + 0x7fffu + ((v.u >> 16) & 1u);  // RNE
  return (u16)(r >> 16);
}

// async global->LDS, 16B per lane; LDS dest is wave-uniform base + lane*16
#define GLD16(g, l) __builtin_amdgcn_global_load_lds( \
    (const __attribute__((address_space(1))) void*)(g), \
    (__attribute__((address_space(3))) void*)(l), 16, 0, 0)

// gemm1 swizzle (R3/R10-proven, 0 conflicts with 16x16 frags): byte ^= (row&7)<<4
__device__ __forceinline__ const s16x8* fragp(const u16* b, int row, int off){
  return (const s16x8*)((const char*)b + row*128 + (off ^ ((row&7)<<4)));
}
// gemm2 swizzle v2 (R7-measured config)
__device__ __forceinline__ int swz2(int r){
  return (r & 7) ^ (((r >> 3) & 3) << 1);
}
__device__ __forceinline__ const s16x8* fragp2(const u16* b, int row, int off){
  return (const s16x8*)((const char*)b + row*128 + (off ^ (swz2(row)<<4)));
}

#define MFMA16(a,b,c) __builtin_amdgcn_mfma_f32_16x16x32_bf16((a),(b),(c),0,0,0)
#define MFMA32(a,b,c) __builtin_amdgcn_mfma_f32_32x32x16_bf16((a),(b),(c),0,0,0)

// ---------------- init: zero maskbits + tokcnt (tiny, precedes logits/scatter) ---
__global__ void k_init(u64* __restrict__ maskbits, int* __restrict__ tokcnt){
  int gi = blockIdx.x*blockDim.x + threadIdx.x;
  if (gi < NE*32) maskbits[gi] = 0ull;
  if (gi < TK) tokcnt[gi] = 0;
}

// ------- convert x + all weights fp32 -> bf16 (single grid-stride stream) --------
__global__ void k_cvtw(const float* __restrict__ x,
                       const float* __restrict__ wg, const float* __restrict__ wu,
                       const float* __restrict__ wd, const float* __restrict__ swg,
                       const float* __restrict__ swu, const float* __restrict__ swd,
                       u16* __restrict__ xb,
                       u16* __restrict__ wgb, u16* __restrict__ wub, u16* __restrict__ wdb){
  const size_t nx = (size_t)TK*HD/4;
  const size_t nbig = (size_t)NE*IH/4, nsml = IH/4;
  const size_t total = nx + 3*nbig + 3*nsml;
  for (size_t i = (size_t)blockIdx.x*blockDim.x + threadIdx.x; i < total;
       i += (size_t)gridDim.x*blockDim.x){
    const float4* src; ushort4* dst; size_t j = i;
    if (j < nx){ src=(const float4*)x + j; dst=(ushort4*)xb + j; }
    else if ((j-=nx) < nbig){ src=(const float4*)wg + j;  dst=(ushort4*)wgb + j; }
    else if ((j-=nbig) < nbig){ src=(const float4*)wu + j;  dst=(ushort4*)wub + j; }
    else if ((j-=nbig) < nbig){ src=(const float4*)wd + j;  dst=(ushort4*)wdb + j; }
    else if ((j-=nbig) < nsml){ src=(const float4*)swg + j; dst=(ushort4*)wgb + nbig + j; }
    else if ((j-=nsml) < nsml){ src=(const float4*)swu + j; dst=(ushort4*)wub + nbig + j; }
    else { j-=nsml; src=(const float4*)swd + j; dst=(ushort4*)wdb + nbig + j; }
    float4 f = *src;
    ushort4 o; o.x=f2bf(f.x); o.y=f2bf(f.y); o.z=f2bf(f.z); o.w=f2bf(f.w);
    *dst = o;
  }
}

// ---------------- router: logits + sigmoid + top-4 select (float4 loads) ---------
__global__ __launch_bounds__(256) void k_logits(const float* __restrict__ x,
                                                const float* __restrict__ gw,
                                                const float* __restrict__ bias,
                                                float* __restrict__ wdense,
                                                u64* __restrict__ maskbits){
  int t = blockIdx.x, tid = threadIdx.x;
  int lane = tid & 63, wv = tid >> 6;
  const float* xr = x + (size_t)t*HD;
  float acc[NE];
  #pragma unroll
  for (int e=0;e<NE;e++) acc[e]=0.f;
  for (int k = tid*4; k < HD; k += 1024){
    float4 xv = *(const float4*)(xr + k);
    #pragma unroll
    for (int e=0;e<NE;e++){
      float4 gv = *(const float4*)(gw + e*HD + k);
      acc[e] += xv.x*gv.x + xv.y*gv.y + xv.z*gv.z + xv.w*gv.w;
    }
  }
  __shared__ float red[NE][4];
  #pragma unroll
  for (int e=0;e<NE;e++){
    float v = acc[e];
    #pragma unroll
    for (int off=32;off>0;off>>=1) v += __shfl_down(v, off, 64);
    if (lane==0) red[e][wv] = v;
  }
  __syncthreads();
  if (tid == 0){
    float sc[NE], bs[NE];
    #pragma unroll
    for (int e=0;e<NE;e++){
      float l = red[e][0]+red[e][1]+red[e][2]+red[e][3];
      float s = 1.f/(1.f+expf(-l));
      sc[e]=s; bs[e]=s+bias[e];
    }
    int idx[TOPK]; float wsum=0.f; unsigned used=0;
    for (int k=0;k<TOPK;k++){
      int best=0; float bv=-1e30f;
      for (int e=0;e<NE;e++) if (!((used>>e)&1u) && bs[e] > bv){ bv=bs[e]; best=e; }
      used |= 1u<<best; idx[k]=best; wsum += sc[best];
    }
    float inv = 1.f/wsum;
    for (int k=0;k<TOPK;k++){
      int e = idx[k];
      wdense[t*NE + e] = sc[e]*inv;
      atomicOr(&maskbits[e*32 + (t>>6)], 1ull << (t&63));
    }
  }
}

// ---- parallel scan: popcounts in parallel, per-expert scans, tiny serial tail ----
__global__ __launch_bounds__(512) void k_scan(const u64* __restrict__ maskbits,
                                              int* __restrict__ counts,
                                              int* __restrict__ offsets,
                                              int* __restrict__ wordpfx,
                                              int* __restrict__ tiles){
  __shared__ int wc[NE*32];
  __shared__ int cnt_s[NE];
  int tid = threadIdx.x;
  wc[tid] = __popcll(maskbits[tid]);          // 512 parallel loads+popcounts
  __syncthreads();
  if (tid < NE){
    int c = 0;
    #pragma unroll
    for (int w=0; w<32; w++){ int v = wc[tid*32+w]; wordpfx[tid*32+w] = c; c += v; }
    cnt_s[tid] = c; counts[tid] = c;
  }
  __syncthreads();
  if (tid == 0){
    int acc = 0;
    for (int e=0;e<NE;e++){ offsets[e] = acc; acc += cnt_s[e]; }
    offsets[NE] = acc;   // == SLOTS
    counts[NE] = TK;     // shared expert
    int nt = 0;
    for (int g=0; g<NG; g++){
      int c = (g<NE) ? cnt_s[g] : TK;
      for (int mt=0; mt*128 < c && nt < MAXT; mt++) tiles[nt++] = (g<<8) | mt;
    }
    for (; nt<MAXT; nt++) tiles[nt] = -1;
  }
}

// deterministic compaction via popcount rank; also token->slot list
__global__ void k_scatter(const u64* __restrict__ maskbits, const int* __restrict__ offsets,
                          const int* __restrict__ wordpfx, const float* __restrict__ wdense,
                          int* __restrict__ rowtok, float* __restrict__ roww,
                          int* __restrict__ tokcnt, int* __restrict__ tok4){
  int t = blockIdx.x*blockDim.x + threadIdx.x;
  int e = blockIdx.y;
  if (t >= TK) return;
  if (e == NE){ rowtok[offsets[NE]+t] = t; roww[offsets[NE]+t] = 1.f; return; }
  u64 w = maskbits[e*32 + (t>>6)];
  if ((w >> (t&63)) & 1ull){
    int pos = offsets[e] + wordpfx[e*32 + (t>>6)] + __popcll(w & ((1ull << (t&63)) - 1ull));
    rowtok[pos] = t; roww[pos] = wdense[t*NE + e];
    int r = atomicAdd(&tokcnt[t], 1);          // order arbitrary; sum is order-free
    tok4[t*TOPK + r] = pos;
  }
}

// ============ GEMM1 (R10/R11/R14-measured best): P = silu(X Wg^T)*(X Wu^T)*roww ===
// BM=128, BN=64 (gate+up), BK=64; 16x16x32 MFMA; global_load_lds; swizzled LDS
__global__ __launch_bounds__(256) void k_gemm1b(
    const u16* __restrict__ xb, const u16* __restrict__ wgb, const u16* __restrict__ wub,
    const int* __restrict__ counts, const int* __restrict__ offsets,
    const int* __restrict__ rowtok, const float* __restrict__ roww,
    const int* __restrict__ tiles, u16* __restrict__ P)
{
  int te = tiles[blockIdx.y];
  if (te < 0) return;
  int g = te >> 8, mt = te & 255;
  int cnt = counts[g];
  int n0 = blockIdx.x*64;
  int base = offsets[g];
  const u16* wg16 = wgb + (size_t)g*IH;
  const u16* wu16 = wub + (size_t)g*IH;

  __shared__ u16 lsA[128*64];
  __shared__ u16 lsG[64*64];
  __shared__ u16 lsU[64*64];

  int tid = threadIdx.x, lane = tid & 63, wv = tid >> 6;
  int wm = (wv>>1)*64, wn = (wv&1)*32;
  int rl = lane & 15, hi = lane >> 4;

  f32x4 accg[4][2] = {}; f32x4 accu[4][2] = {};

  // staging descriptors (source pre-swizzled: col block = cb ^ (r&7))
  const u16* aSrc[4];
  #pragma unroll
  for (int i=0;i<4;i++){
    int b = i*256 + tid, r = b>>3, cb = b&7;
    int m = mt*128 + r; if (m >= cnt) m = cnt-1;
    int tok = rowtok[base + m];
    aSrc[i] = xb + (size_t)tok*HD + ((cb ^ (r&7))<<3);
  }
  const u16 *gSrc[2], *uSrc[2];
  #pragma unroll
  for (int i=0;i<2;i++){
    int b = i*256 + tid, r = b>>3, cb = b&7;
    size_t off = (size_t)(n0 + r)*HD + ((cb ^ (r&7))<<3);
    gSrc[i] = wg16 + off; uSrc[i] = wu16 + off;
  }

  for (int k0=0; k0<HD; k0+=64){
    #pragma unroll
    for (int i=0;i<4;i++) GLD16(aSrc[i]+k0, lsA + (i*256 + wv*64)*8);
    #pragma unroll
    for (int i=0;i<2;i++) GLD16(gSrc[i]+k0, lsG + (i*256 + wv*64)*8);
    #pragma unroll
    for (int i=0;i<2;i++) GLD16(uSrc[i]+k0, lsU + (i*256 + wv*64)*8);
    __syncthreads();
    #pragma unroll
    for (int ks=0; ks<2; ++ks){
      int off = ks*64 + hi*16;
      s16x8 af[4];
      #pragma unroll
      for (int mi=0;mi<4;mi++) af[mi] = *fragp(lsA, wm+16*mi+rl, off);
      #pragma unroll
      for (int ni=0;ni<2;ni++){
        s16x8 bg = *fragp(lsG, wn+16*ni+rl, off);
        s16x8 bu = *fragp(lsU, wn+16*ni+rl, off);
        #pragma unroll
        for (int mi=0;mi<4;mi++){
          accg[mi][ni] = MFMA16(af[mi], bg, accg[mi][ni]);
          accu[mi][ni] = MFMA16(af[mi], bu, accu[mi][ni]);
        }
      }
    }
    __syncthreads();
  }
  // epilogue: SwiGLU * token weight -> bf16 P
  int rl4 = hi*4, cl = rl;
  #pragma unroll
  for (int mi=0;mi<4;mi++){
    #pragma unroll
    for (int j=0;j<4;j++){
      int m = mt*128 + wm + mi*16 + rl4 + j;
      if (m < cnt){
        int slot = base + m;
        float wgt = roww[slot];
        #pragma unroll
        for (int ni=0;ni<2;ni++){
          float gv = accg[mi][ni][j], uv = accu[mi][ni][j];
          float pv = gv/(1.f+expf(-gv))*uv*wgt;
          P[(size_t)slot*ID + n0 + wn + ni*16 + cl] = f2bf(pv);
        }
      }
    }
  }
}

// ============ GEMM2 (R7/R11/R14-measured best): R[slot] = P[slot] @ Wd^T ==========
// BM=128, BN=256, BK=64; 32x32x16 MFMA, per-wave 64x128; bf16 partials, no atomics
__global__ __launch_bounds__(256, 2) void k_gemm2b(
    const u16* __restrict__ P, const u16* __restrict__ wdb,
    const int* __restrict__ counts, const int* __restrict__ offsets,
    const int* __restrict__ tiles, u16* __restrict__ R)
{
  int te = tiles[blockIdx.y];
  if (te < 0) return;
  int g = te >> 8, mt = te & 255;
  int cnt = counts[g];
  int base = offsets[g];
  int n0 = blockIdx.x*256;
  const u16* wd16 = wdb + (size_t)g*IH;

  __shared__ u16 lsA[128*64];   // 16 KB
  __shared__ u16 lsB[256*64];   // 32 KB

  int tid = threadIdx.x, lane = tid & 63, wv = tid >> 6;
  int wm = (wv>>1)*64, wn = (wv&1)*128;
  int rl = lane & 31, hi = lane >> 5;
  f32x16 acc[2][4] = {};

  const u16* aSrc[4];
  #pragma unroll
  for (int i=0;i<4;i++){
    int b = i*256 + tid, r = b>>3, cb = b&7;
    int m = mt*128 + r; if (m >= cnt) m = cnt-1;
    aSrc[i] = P + (size_t)(base + m)*ID + ((cb ^ swz2(r))<<3);
  }
  const u16* bSrc[8];
  #pragma unroll
  for (int i=0;i<8;i++){
    int b = i*256 + tid, r = b>>3, cb = b&7;
    bSrc[i] = wd16 + (size_t)(n0 + r)*ID + ((cb ^ swz2(r))<<3);
  }

  for (int t=0; t<ID/64; ++t){
    int k0 = t*64;
    #pragma unroll
    for (int i=0;i<4;i++) GLD16(aSrc[i]+k0, lsA + (i*256 + wv*64)*8);
    #pragma unroll
    for (int i=0;i<8;i++) GLD16(bSrc[i]+k0, lsB + (i*256 + wv*64)*8);
    asm volatile("s_waitcnt vmcnt(0)" ::: "memory");
    __builtin_amdgcn_s_barrier();
    #pragma unroll
    for (int s=0; s<4; ++s){
      int off = s*32 + hi*16;
      s16x8 af[2], bf[4];
      af[0] = *fragp2(lsA, wm + rl, off);
      af[1] = *fragp2(lsA, wm + 32 + rl, off);
      #pragma unroll
      for (int nj=0;nj<4;nj++) bf[nj] = *fragp2(lsB, wn + nj*32 + rl, off);
      #pragma unroll
      for (int mi=0;mi<2;mi++)
        #pragma unroll
        for (int nj=0;nj<4;nj++)
          acc[mi][nj] = MFMA32(af[mi], bf[nj], acc[mi][nj]);
    }
    asm volatile("s_waitcnt lgkmcnt(0)" ::: "memory");
    __builtin_amdgcn_s_barrier();
  }
  #pragma unroll
  for (int mi=0;mi<2;mi++){
    #pragma unroll
    for (int r=0;r<16;r++){
      int rowb = wm + mi*32 + (r&3) + 8*(r>>2) + 4*hi;
      int m = mt*128 + rowb;
      if (m < cnt){
        int slot = base + m;
        u16* rrow = R + (size_t)slot*HD + n0 + wn + rl;
        #pragma unroll
        for (int nj=0;nj<4;nj++) rrow[nj*32] = f2bf(acc[mi][nj][r]);
      }
    }
  }
}

// ============ reduce: out[t] = R[shared_slot(t)] + sum_k R[tok4[t][k]] ============
__global__ __launch_bounds__(256) void k_reduce(const u16* __restrict__ R,
                                                const int* __restrict__ tok4,
                                                float* __restrict__ out){
  int t = blockIdx.x;
  int c0 = threadIdx.x * 8;           // 256 threads x 8 cols = 2048
  int s0 = tok4[t*TOPK+0], s1 = tok4[t*TOPK+1], s2 = tok4[t*TOPK+2], s3 = tok4[t*TOPK+3];
  const ushort4* p0 = (const ushort4*)(R + (size_t)s0*HD + c0);
  const ushort4* p1 = (const ushort4*)(R + (size_t)s1*HD + c0);
  const ushort4* p2 = (const ushort4*)(R + (size_t)s2*HD + c0);
  const ushort4* p3 = (const ushort4*)(R + (size_t)s3*HD + c0);
  const ushort4* ps = (const ushort4*)(R + (size_t)(SLOTS + t)*HD + c0);
  float* o = out + (size_t)t*HD + c0;
  #pragma unroll
  for (int h=0; h<2; h++){
    ushort4 a = p0[h], b = p1[h], c = p2[h], d = p3[h], e = ps[h];
    #pragma unroll
    for (int j=0;j<4;j++){
      u16 ua = ((const u16*)&a)[j], ub = ((const u16*)&b)[j];
      u16 uc = ((const u16*)&c)[j], ud = ((const u16*)&d)[j], ue = ((const u16*)&e)[j];
      union { uint32_t u; float f; } w;
      float v;
      w.u = (uint32_t)ua<<16; v  = w.f;
      w.u = (uint32_t)ub<<16; v += w.f;
      w.u = (uint32_t)uc<<16; v += w.f;
      w.u = (uint32_t)ud<<16; v += w.f;
      w.u = (uint32_t)ue<<16; v += w.f;
      o[h*4 + j] = v;
    }
  }
}

// ---------------- host ----------------

extern "C" void kernel_launch(void* const* d_in, const int* in_sizes, int n_in,
                              void* d_out, int out_size, void* d_ws, size_t ws_size,
                              hipStream_t stream){
  (void)in_sizes; (void)n_in; (void)ws_size; (void)out_size;
  const float* x       = (const float*)d_in[0];
  const float* gate_w  = (const float*)d_in[1];
  const float* ebias   = (const float*)d_in[2];
  const float* w_gate  = (const float*)d_in[3];
  const float* w_up    = (const float*)d_in[4];
  const float* w_down  = (const float*)d_in[5];
  const float* sw_gate = (const float*)d_in[6];
  const float* sw_up   = (const float*)d_in[7];
  const float* sw_down = (const float*)d_in[8];
  float* out = (float*)d_out;

  char* p = (char*)d_ws;
  auto alloc = [&](size_t bytes)->char*{ char* r = p; p += (bytes + 255) & ~(size_t)255; return r; };
  u16*   xb       = (u16*)  alloc((size_t)TK*HD*2);
  u16*   P        = (u16*)  alloc((size_t)ROWS_ALL*ID*2);
  float* wdense   = (float*)alloc((size_t)TK*NE*4);
  u64*   maskbits = (u64*)  alloc((size_t)NE*32*8);
  int*   wordpfx  = (int*)  alloc((size_t)NE*32*4);
  int*   counts   = (int*)  alloc(64);
  int*   offsets  = (int*)  alloc(64);
  int*   tiles    = (int*)  alloc(MAXT*4);
  int*   rowtok   = (int*)  alloc((size_t)ROWS_ALL*4);
  float* roww     = (float*)alloc((size_t)ROWS_ALL*4);
  int*   tokcnt   = (int*)  alloc((size_t)TK*4);
  int*   tok4     = (int*)  alloc((size_t)TK*TOPK*4);
  size_t slab = (size_t)NG*IH*2;
  u16* wgb = (u16*)alloc(slab);
  u16* wub = (u16*)alloc(slab);
  u16* wdb = (u16*)alloc(slab);
  // R (40 MB) aliases wgb (71 MB): wgb dead after gemm1, regenerated each call.
  u16* R = wgb;

  k_init<<<8, 256, 0, stream>>>(maskbits, tokcnt);
  k_cvtw<<<2048, 256, 0, stream>>>(x, w_gate, w_up, w_down, sw_gate, sw_up, sw_down,
                                   xb, wgb, wub, wdb);
  k_logits<<<TK, 256, 0, stream>>>(x, gate_w, ebias, wdense, maskbits);
  k_scan<<<1, 512, 0, stream>>>(maskbits, counts, offsets, wordpfx, tiles);
  k_scatter<<<dim3(TK/256, NG), 256, 0, stream>>>(maskbits, offsets, wordpfx, wdense,
                                                  rowtok, roww, tokcnt, tok4);

  dim3 g1(ID/64, MAXT);      // 16 col-blocks x 128-row tiles
  k_gemm1b<<<g1, 256, 0, stream>>>(xb, wgb, wub, counts, offsets, rowtok, roww, tiles, P);
  dim3 g2(HD/256, MAXT);     // 8 col-blocks x 128-row tiles
  k_gemm2b<<<g2, 256, 0, stream>>>(P, wdb, counts, offsets, tiles, R);
  k_reduce<<<TK, 256, 0, stream>>>(R, tok4, out);
}

// Round 16
// 377.855 us; speedup vs baseline: 1.0679x; 1.0679x over previous
//
#include <hip/hip_runtime.h>
#include <hip/hip_bf16.h>
#include <cstdint>

#define TK 2048      // tokens (2*1024)
#define HD 2048      // hidden
#define ID 1024      // intermediate
#define NE 16        // routed experts
#define NG 17        // groups incl shared expert (g==16)
#define TOPK 4
#define SLOTS (TK*TOPK)       // 8192 routed rows
#define ROWS_ALL (SLOTS+TK)   // 10240 incl shared
#define IH (ID*HD)            // 2,097,152 elems per expert matrix
#define MAXT 96               // max 128-row M-tiles across all groups

typedef __attribute__((ext_vector_type(4))) float f32x4;
typedef __attribute__((ext_vector_type(16))) float f32x16;
typedef __attribute__((ext_vector_type(8))) short s16x8;
typedef unsigned short u16;
typedef unsigned long long u64;

__device__ __forceinline__ u16 f2bf(float f){
  union { float f; uint32_t u; } v; v.f = f;
  uint32_t r = v.u + 0x7fffu + ((v.u >> 16) & 1u);  // RNE
  return (u16)(r >> 16);
}

// async global->LDS, 16B per lane; LDS dest is wave-uniform base + lane*16
#define GLD16(g, l) __builtin_amdgcn_global_load_lds( \
    (const __attribute__((address_space(1))) void*)(g), \
    (__attribute__((address_space(3))) void*)(l), 16, 0, 0)

// gemm1 swizzle (R3/R10-proven, 0 conflicts with 16x16 frags): byte ^= (row&7)<<4
__device__ __forceinline__ const s16x8* fragp(const u16* b, int row, int off){
  return (const s16x8*)((const char*)b + row*128 + (off ^ ((row&7)<<4)));
}
// gemm2 swizzle v2 (R7-measured config)
__device__ __forceinline__ int swz2(int r){
  return (r & 7) ^ (((r >> 3) & 3) << 1);
}
__device__ __forceinline__ const s16x8* fragp2(const u16* b, int row, int off){
  return (const s16x8*)((const char*)b + row*128 + (off ^ (swz2(row)<<4)));
}

#define MFMA16(a,b,c) __builtin_amdgcn_mfma_f32_16x16x32_bf16((a),(b),(c),0,0,0)
#define MFMA32(a,b,c) __builtin_amdgcn_mfma_f32_32x32x16_bf16((a),(b),(c),0,0,0)

// ---------------- prep: init maskbits+tokcnt, convert x ----------------
__global__ void k_prep(const float* __restrict__ x, u16* __restrict__ xb,
                       u64* __restrict__ maskbits, int* __restrict__ tokcnt){
  int gi = blockIdx.x*blockDim.x + threadIdx.x;
  int st = gridDim.x*blockDim.x;
  if (gi < NE*32) maskbits[gi] = 0ull;
  if (gi < TK) tokcnt[gi] = 0;
  for (int i=gi; i<TK*HD/4; i+=st){
    float4 f = ((const float4*)x)[i];
    ushort4 o; o.x=f2bf(f.x); o.y=f2bf(f.y); o.z=f2bf(f.z); o.w=f2bf(f.w);
    ((ushort4*)xb)[i] = o;
  }
}

// ---------------- convert all weights fp32 -> bf16 (one kernel, 3 slabs) --------
__global__ void k_cvtw(const float* __restrict__ wg, const float* __restrict__ wu,
                       const float* __restrict__ wd, const float* __restrict__ swg,
                       const float* __restrict__ swu, const float* __restrict__ swd,
                       u16* __restrict__ wgb, u16* __restrict__ wub, u16* __restrict__ wdb){
  const size_t nbig = (size_t)NE*IH/4, nsml = IH/4;
  const size_t total = 3*nbig + 3*nsml;
  for (size_t i = (size_t)blockIdx.x*blockDim.x + threadIdx.x; i < total;
       i += (size_t)gridDim.x*blockDim.x){
    const float4* src; ushort4* dst; size_t j = i;
    if (j < nbig){ src=(const float4*)wg + j;  dst=(ushort4*)wgb + j; }
    else if ((j-=nbig) < nbig){ src=(const float4*)wu + j;  dst=(ushort4*)wub + j; }
    else if ((j-=nbig) < nbig){ src=(const float4*)wd + j;  dst=(ushort4*)wdb + j; }
    else if ((j-=nbig) < nsml){ src=(const float4*)swg + j; dst=(ushort4*)wgb + nbig + j; }
    else if ((j-=nsml) < nsml){ src=(const float4*)swu + j; dst=(ushort4*)wub + nbig + j; }
    else { j-=nsml; src=(const float4*)swd + j; dst=(ushort4*)wdb + nbig + j; }
    float4 f = *src;
    ushort4 o; o.x=f2bf(f.x); o.y=f2bf(f.y); o.z=f2bf(f.z); o.w=f2bf(f.w);
    *dst = o;
  }
}

// ---------------- router: logits + sigmoid + top-4 select (float4 loads) ---------
__global__ __launch_bounds__(256) void k_logits(const float* __restrict__ x,
                                                const float* __restrict__ gw,
                                                const float* __restrict__ bias,
                                                float* __restrict__ wdense,
                                                u64* __restrict__ maskbits){
  int t = blockIdx.x, tid = threadIdx.x;
  int lane = tid & 63, wv = tid >> 6;
  const float* xr = x + (size_t)t*HD;
  float acc[NE];
  #pragma unroll
  for (int e=0;e<NE;e++) acc[e]=0.f;
  for (int k = tid*4; k < HD; k += 1024){
    float4 xv = *(const float4*)(xr + k);
    #pragma unroll
    for (int e=0;e<NE;e++){
      float4 gv = *(const float4*)(gw + e*HD + k);
      acc[e] += xv.x*gv.x + xv.y*gv.y + xv.z*gv.z + xv.w*gv.w;
    }
  }
  __shared__ float red[NE][4];
  #pragma unroll
  for (int e=0;e<NE;e++){
    float v = acc[e];
    #pragma unroll
    for (int off=32;off>0;off>>=1) v += __shfl_down(v, off, 64);
    if (lane==0) red[e][wv] = v;
  }
  __syncthreads();
  if (tid == 0){
    float sc[NE], bs[NE];
    #pragma unroll
    for (int e=0;e<NE;e++){
      float l = red[e][0]+red[e][1]+red[e][2]+red[e][3];
      float s = 1.f/(1.f+expf(-l));
      sc[e]=s; bs[e]=s+bias[e];
    }
    int idx[TOPK]; float wsum=0.f; unsigned used=0;
    for (int k=0;k<TOPK;k++){
      int best=0; float bv=-1e30f;
      for (int e=0;e<NE;e++) if (!((used>>e)&1u) && bs[e] > bv){ bv=bs[e]; best=e; }
      used |= 1u<<best; idx[k]=best; wsum += sc[best];
    }
    float inv = 1.f/wsum;
    for (int k=0;k<TOPK;k++){
      int e = idx[k];
      wdense[t*NE + e] = sc[e]*inv;
      atomicOr(&maskbits[e*32 + (t>>6)], 1ull << (t&63));
    }
  }
}

// ---- parallel scan: popcounts in parallel, per-expert scans, tiny serial tail ----
__global__ __launch_bounds__(512) void k_scan(const u64* __restrict__ maskbits,
                                              int* __restrict__ counts,
                                              int* __restrict__ offsets,
                                              int* __restrict__ wordpfx,
                                              int* __restrict__ tiles){
  __shared__ int wc[NE*32];
  __shared__ int cnt_s[NE];
  int tid = threadIdx.x;
  wc[tid] = __popcll(maskbits[tid]);          // 512 parallel loads+popcounts
  __syncthreads();
  if (tid < NE){
    int c = 0;
    #pragma unroll
    for (int w=0; w<32; w++){ int v = wc[tid*32+w]; wordpfx[tid*32+w] = c; c += v; }
    cnt_s[tid] = c; counts[tid] = c;
  }
  __syncthreads();
  if (tid == 0){
    int acc = 0;
    for (int e=0;e<NE;e++){ offsets[e] = acc; acc += cnt_s[e]; }
    offsets[NE] = acc;   // == SLOTS
    counts[NE] = TK;     // shared expert
    int nt = 0;
    for (int g=0; g<NG; g++){
      int c = (g<NE) ? cnt_s[g] : TK;
      for (int mt=0; mt*128 < c && nt < MAXT; mt++) tiles[nt++] = (g<<8) | mt;
    }
    for (; nt<MAXT; nt++) tiles[nt] = -1;
  }
}

// deterministic compaction via popcount rank; also token->slot list
__global__ void k_scatter(const u64* __restrict__ maskbits, const int* __restrict__ offsets,
                          const int* __restrict__ wordpfx, const float* __restrict__ wdense,
                          int* __restrict__ rowtok, float* __restrict__ roww,
                          int* __restrict__ tokcnt, int* __restrict__ tok4){
  int t = blockIdx.x*blockDim.x + threadIdx.x;
  int e = blockIdx.y;
  if (t >= TK) return;
  if (e == NE){ rowtok[offsets[NE]+t] = t; roww[offsets[NE]+t] = 1.f; return; }
  u64 w = maskbits[e*32 + (t>>6)];
  if ((w >> (t&63)) & 1ull){
    int pos = offsets[e] + wordpfx[e*32 + (t>>6)] + __popcll(w & ((1ull << (t&63)) - 1ull));
    rowtok[pos] = t; roww[pos] = wdense[t*NE + e];
    int r = atomicAdd(&tokcnt[t], 1);          // order arbitrary; sum is order-free
    tok4[t*TOPK + r] = pos;
  }
}

// ============ GEMM1 (R10/R11/R14-measured best): P = silu(X Wg^T)*(X Wu^T)*roww ===
// BM=128, BN=64 (gate+up), BK=64; 16x16x32 MFMA; global_load_lds; swizzled LDS
__global__ __launch_bounds__(256) void k_gemm1b(
    const u16* __restrict__ xb, const u16* __restrict__ wgb, const u16* __restrict__ wub,
    const int* __restrict__ counts, const int* __restrict__ offsets,
    const int* __restrict__ rowtok, const float* __restrict__ roww,
    const int* __restrict__ tiles, u16* __restrict__ P)
{
  int te = tiles[blockIdx.y];
  if (te < 0) return;
  int g = te >> 8, mt = te & 255;
  int cnt = counts[g];
  int n0 = blockIdx.x*64;
  int base = offsets[g];
  const u16* wg16 = wgb + (size_t)g*IH;
  const u16* wu16 = wub + (size_t)g*IH;

  __shared__ u16 lsA[128*64];
  __shared__ u16 lsG[64*64];
  __shared__ u16 lsU[64*64];

  int tid = threadIdx.x, lane = tid & 63, wv = tid >> 6;
  int wm = (wv>>1)*64, wn = (wv&1)*32;
  int rl = lane & 15, hi = lane >> 4;

  f32x4 accg[4][2] = {}; f32x4 accu[4][2] = {};

  // staging descriptors (source pre-swizzled: col block = cb ^ (r&7))
  const u16* aSrc[4];
  #pragma unroll
  for (int i=0;i<4;i++){
    int b = i*256 + tid, r = b>>3, cb = b&7;
    int m = mt*128 + r; if (m >= cnt) m = cnt-1;
    int tok = rowtok[base + m];
    aSrc[i] = xb + (size_t)tok*HD + ((cb ^ (r&7))<<3);
  }
  const u16 *gSrc[2], *uSrc[2];
  #pragma unroll
  for (int i=0;i<2;i++){
    int b = i*256 + tid, r = b>>3, cb = b&7;
    size_t off = (size_t)(n0 + r)*HD + ((cb ^ (r&7))<<3);
    gSrc[i] = wg16 + off; uSrc[i] = wu16 + off;
  }

  for (int k0=0; k0<HD; k0+=64){
    #pragma unroll
    for (int i=0;i<4;i++) GLD16(aSrc[i]+k0, lsA + (i*256 + wv*64)*8);
    #pragma unroll
    for (int i=0;i<2;i++) GLD16(gSrc[i]+k0, lsG + (i*256 + wv*64)*8);
    #pragma unroll
    for (int i=0;i<2;i++) GLD16(uSrc[i]+k0, lsU + (i*256 + wv*64)*8);
    __syncthreads();
    #pragma unroll
    for (int ks=0; ks<2; ++ks){
      int off = ks*64 + hi*16;
      s16x8 af[4];
      #pragma unroll
      for (int mi=0;mi<4;mi++) af[mi] = *fragp(lsA, wm+16*mi+rl, off);
      #pragma unroll
      for (int ni=0;ni<2;ni++){
        s16x8 bg = *fragp(lsG, wn+16*ni+rl, off);
        s16x8 bu = *fragp(lsU, wn+16*ni+rl, off);
        #pragma unroll
        for (int mi=0;mi<4;mi++){
          accg[mi][ni] = MFMA16(af[mi], bg, accg[mi][ni]);
          accu[mi][ni] = MFMA16(af[mi], bu, accu[mi][ni]);
        }
      }
    }
    __syncthreads();
  }
  // epilogue: SwiGLU * token weight -> bf16 P
  int rl4 = hi*4, cl = rl;
  #pragma unroll
  for (int mi=0;mi<4;mi++){
    #pragma unroll
    for (int j=0;j<4;j++){
      int m = mt*128 + wm + mi*16 + rl4 + j;
      if (m < cnt){
        int slot = base + m;
        float wgt = roww[slot];
        #pragma unroll
        for (int ni=0;ni<2;ni++){
          float gv = accg[mi][ni][j], uv = accu[mi][ni][j];
          float pv = gv/(1.f+expf(-gv))*uv*wgt;
          P[(size_t)slot*ID + n0 + wn + ni*16 + cl] = f2bf(pv);
        }
      }
    }
  }
}

// ============ GEMM2 (R7/R11/R14-measured best): R[slot] = P[slot] @ Wd^T ==========
// BM=128, BN=256, BK=64; 32x32x16 MFMA, per-wave 64x128; bf16 partials, no atomics
__global__ __launch_bounds__(256, 2) void k_gemm2b(
    const u16* __restrict__ P, const u16* __restrict__ wdb,
    const int* __restrict__ counts, const int* __restrict__ offsets,
    const int* __restrict__ tiles, u16* __restrict__ R)
{
  int te = tiles[blockIdx.y];
  if (te < 0) return;
  int g = te >> 8, mt = te & 255;
  int cnt = counts[g];
  int base = offsets[g];
  int n0 = blockIdx.x*256;
  const u16* wd16 = wdb + (size_t)g*IH;

  __shared__ u16 lsA[128*64];   // 16 KB
  __shared__ u16 lsB[256*64];   // 32 KB

  int tid = threadIdx.x, lane = tid & 63, wv = tid >> 6;
  int wm = (wv>>1)*64, wn = (wv&1)*128;
  int rl = lane & 31, hi = lane >> 5;
  f32x16 acc[2][4] = {};

  const u16* aSrc[4];
  #pragma unroll
  for (int i=0;i<4;i++){
    int b = i*256 + tid, r = b>>3, cb = b&7;
    int m = mt*128 + r; if (m >= cnt) m = cnt-1;
    aSrc[i] = P + (size_t)(base + m)*ID + ((cb ^ swz2(r))<<3);
  }
  const u16* bSrc[8];
  #pragma unroll
  for (int i=0;i<8;i++){
    int b = i*256 + tid, r = b>>3, cb = b&7;
    bSrc[i] = wd16 + (size_t)(n0 + r)*ID + ((cb ^ swz2(r))<<3);
  }

  for (int t=0; t<ID/64; ++t){
    int k0 = t*64;
    #pragma unroll
    for (int i=0;i<4;i++) GLD16(aSrc[i]+k0, lsA + (i*256 + wv*64)*8);
    #pragma unroll
    for (int i=0;i<8;i++) GLD16(bSrc[i]+k0, lsB + (i*256 + wv*64)*8);
    asm volatile("s_waitcnt vmcnt(0)" ::: "memory");
    __builtin_amdgcn_s_barrier();
    #pragma unroll
    for (int s=0; s<4; ++s){
      int off = s*32 + hi*16;
      s16x8 af[2], bf[4];
      af[0] = *fragp2(lsA, wm + rl, off);
      af[1] = *fragp2(lsA, wm + 32 + rl, off);
      #pragma unroll
      for (int nj=0;nj<4;nj++) bf[nj] = *fragp2(lsB, wn + nj*32 + rl, off);
      #pragma unroll
      for (int mi=0;mi<2;mi++)
        #pragma unroll
        for (int nj=0;nj<4;nj++)
          acc[mi][nj] = MFMA32(af[mi], bf[nj], acc[mi][nj]);
    }
    asm volatile("s_waitcnt lgkmcnt(0)" ::: "memory");
    __builtin_amdgcn_s_barrier();
  }
  #pragma unroll
  for (int mi=0;mi<2;mi++){
    #pragma unroll
    for (int r=0;r<16;r++){
      int rowb = wm + mi*32 + (r&3) + 8*(r>>2) + 4*hi;
      int m = mt*128 + rowb;
      if (m < cnt){
        int slot = base + m;
        u16* rrow = R + (size_t)slot*HD + n0 + wn + rl;
        #pragma unroll
        for (int nj=0;nj<4;nj++) rrow[nj*32] = f2bf(acc[mi][nj][r]);
      }
    }
  }
}

// ============ reduce: out[t] = R[shared_slot(t)] + sum_k R[tok4[t][k]] ============
__global__ __launch_bounds__(256) void k_reduce(const u16* __restrict__ R,
                                                const int* __restrict__ tok4,
                                                float* __restrict__ out){
  int t = blockIdx.x;
  int c0 = threadIdx.x * 8;           // 256 threads x 8 cols = 2048
  int s0 = tok4[t*TOPK+0], s1 = tok4[t*TOPK+1], s2 = tok4[t*TOPK+2], s3 = tok4[t*TOPK+3];
  const ushort4* p0 = (const ushort4*)(R + (size_t)s0*HD + c0);
  const ushort4* p1 = (const ushort4*)(R + (size_t)s1*HD + c0);
  const ushort4* p2 = (const ushort4*)(R + (size_t)s2*HD + c0);
  const ushort4* p3 = (const ushort4*)(R + (size_t)s3*HD + c0);
  const ushort4* ps = (const ushort4*)(R + (size_t)(SLOTS + t)*HD + c0);
  float* o = out + (size_t)t*HD + c0;
  #pragma unroll
  for (int h=0; h<2; h++){
    ushort4 a = p0[h], b = p1[h], c = p2[h], d = p3[h], e = ps[h];
    #pragma unroll
    for (int j=0;j<4;j++){
      u16 ua = ((const u16*)&a)[j], ub = ((const u16*)&b)[j];
      u16 uc = ((const u16*)&c)[j], ud = ((const u16*)&d)[j], ue = ((const u16*)&e)[j];
      union { uint32_t u; float f; } w;
      float v;
      w.u = (uint32_t)ua<<16; v  = w.f;
      w.u = (uint32_t)ub<<16; v += w.f;
      w.u = (uint32_t)uc<<16; v += w.f;
      w.u = (uint32_t)ud<<16; v += w.f;
      w.u = (uint32_t)ue<<16; v += w.f;
      o[h*4 + j] = v;
    }
  }
}

// ---------------- host ----------------

extern "C" void kernel_launch(void* const* d_in, const int* in_sizes, int n_in,
                              void* d_out, int out_size, void* d_ws, size_t ws_size,
                              hipStream_t stream){
  (void)in_sizes; (void)n_in; (void)ws_size; (void)out_size;
  const float* x       = (const float*)d_in[0];
  const float* gate_w  = (const float*)d_in[1];
  const float* ebias   = (const float*)d_in[2];
  const float* w_gate  = (const float*)d_in[3];
  const float* w_up    = (const float*)d_in[4];
  const float* w_down  = (const float*)d_in[5];
  const float* sw_gate = (const float*)d_in[6];
  const float* sw_up   = (const float*)d_in[7];
  const float* sw_down = (const float*)d_in[8];
  float* out = (float*)d_out;

  char* p = (char*)d_ws;
  auto alloc = [&](size_t bytes)->char*{ char* r = p; p += (bytes + 255) & ~(size_t)255; return r; };
  u16*   xb       = (u16*)  alloc((size_t)TK*HD*2);
  u16*   P        = (u16*)  alloc((size_t)ROWS_ALL*ID*2);
  float* wdense   = (float*)alloc((size_t)TK*NE*4);
  u64*   maskbits = (u64*)  alloc((size_t)NE*32*8);
  int*   wordpfx  = (int*)  alloc((size_t)NE*32*4);
  int*   counts   = (int*)  alloc(64);
  int*   offsets  = (int*)  alloc(64);
  int*   tiles    = (int*)  alloc(MAXT*4);
  int*   rowtok   = (int*)  alloc((size_t)ROWS_ALL*4);
  float* roww     = (float*)alloc((size_t)ROWS_ALL*4);
  int*   tokcnt   = (int*)  alloc((size_t)TK*4);
  int*   tok4     = (int*)  alloc((size_t)TK*TOPK*4);
  size_t slab = (size_t)NG*IH*2;
  u16* wgb = (u16*)alloc(slab);
  u16* wub = (u16*)alloc(slab);
  u16* wdb = (u16*)alloc(slab);
  // R (40 MB) aliases wgb (71 MB): wgb dead after gemm1, regenerated each call.
  u16* R = wgb;

  k_prep<<<2048, 256, 0, stream>>>(x, xb, maskbits, tokcnt);
  k_cvtw<<<2048, 256, 0, stream>>>(w_gate, w_up, w_down, sw_gate, sw_up, sw_down,
                                   wgb, wub, wdb);
  k_logits<<<TK, 256, 0, stream>>>(x, gate_w, ebias, wdense, maskbits);
  k_scan<<<1, 512, 0, stream>>>(maskbits, counts, offsets, wordpfx, tiles);
  k_scatter<<<dim3(TK/256, NG), 256, 0, stream>>>(maskbits, offsets, wordpfx, wdense,
                                                  rowtok, roww, tokcnt, tok4);

  dim3 g1(ID/64, MAXT);      // 16 col-blocks x 128-row tiles
  k_gemm1b<<<g1, 256, 0, stream>>>(xb, wgb, wub, counts, offsets, rowtok, roww, tiles, P);
  dim3 g2(HD/256, MAXT);     // 8 col-blocks x 128-row tiles
  k_gemm2b<<<g2, 256, 0, stream>>>(P, wdb, counts, offsets, tiles, R);
  k_reduce<<<TK, 256, 0, stream>>>(R, tok4, out);
}